// Round 6
// baseline (180.181 us; speedup 1.0000x reference)
//
#include <hip/hip_runtime.h>
#include <math.h>

// ================== problem constants ==================
#define BATCH   4096
#define NPUMP   4
#define NCH     100
#define RESPLEN 801

// RK4: 32 steps over 50 km (validated: absmax 1.22e-4 vs threshold 2.11e-4).
#define NSTEPS  32
#define DZ_F    1562.5f
#define HDZ_F   781.25f
#define DZ6_F   260.4166666666667f
#define LOSSC   4.605170185988092e-05f   // 0.0002 * ln(10)/10
#define INV256  0.00390625f              // undo the 2^8 G pre-scale

// ================== structure ==========================
// LDS accounting identity (R3/R4/R5): reads/CU-stage = waves/CU x 5, since
// every wave reads full K. So: 4-wave blocks, GB=8, grid 512 -> 2 indep
// blocks/CU = 8 waves/CU (hiding), each wave amortizing its 5 reads over
// TWO row-tiles. Wave 3: tile 6 + the 4 pump rows computed from its own
// resident B fragments (dot2 + shfl_xor butterfly) - no extra reads.
// MFMA B-columns duplicate the 8 batches (broadcast reads, writes gated).
// ROWSTR = 144 f16 = 72 dwords == 8 (mod 32): all b128/b64 LDS ops <=2-way
// bank aliasing (free) - R3's 136 was 8-way on reads.
#define GB      8
#define ROWSTR  144

typedef _Float16 f16;
typedef _Float16 f16x2 __attribute__((ext_vector_type(2)));
typedef _Float16 f16x8 __attribute__((ext_vector_type(8)));
typedef float    f32x4 __attribute__((ext_vector_type(4)));

union u8x { f16x8 v; f16x2 h[4]; };

#define MFMA16(Aa, Bb, Cc) __builtin_amdgcn_mfma_f32_16x16x32_f16((Aa), (Bb), (Cc), 0, 0, 0)

// Gain entry, scaled by 256 (3.2e12 = 1.25e10 * 2^8) so fp16-quantized
// near-diagonal entries stay normal. Consumers multiply y by INV256.
__device__ __forceinline__ float gentry(float fi, float fj, float invfj,
                                        const float* __restrict__ resp_s)
{
    float D    = fj - fi;
    float ad   = fabsf(D);
    float fidx = ad * 2.0e-11f;          // 1/DF
    int   i0   = (int)fidx;
    i0 = i0 > (RESPLEN - 2) ? (RESPLEN - 2) : i0;
    float w  = fidx - (float)i0;
    float g  = resp_s[i0] * (1.0f - w) + resp_s[i0 + 1] * w;
    g = (D < 0.0f) ? -g : g;
    float ratio = fi * invfj;
    float m  = fmaxf(1.0f, ratio);
    return g * m * 3.2e12f;              // (1/EFFECTIVE_AREA) * 256
}

// One RK stage. Reads P (fp16) from Pls[buf], writes next-stage P to
// Pls[buf^1], one barrier. FIRST_/LAST_ are 0/1 literals.
#define STAGE(A_, W_, FIRST_, LAST_)                                           \
  {                                                                            \
    const f16* pb = (const f16*)&Pls[buf][cb][0];                              \
    u8x Bu0, Bu1, Bu2, Bu3;                                                    \
    Bu0.v = *(const f16x8*)(pb + 8 * q);                                       \
    Bu1.v = *(const f16x8*)(pb + 32 + 8 * q);                                  \
    Bu2.v = *(const f16x8*)(pb + 64 + 8 * q);                                  \
    Bu3.v = *(const f16x8*)(pb + 96 + 8 * q);                                  \
    union { uint2 u2; f16x2 h[2]; } ppu;                                       \
    ppu.u2 = *(const uint2*)(pb + 100);                                        \
    if (wid < 3) {                                                             \
      _Pragma("unroll")                                                        \
      for (int t = 0; t < 2; ++t) {                                            \
        f32x4 a01 = {0.f,0.f,0.f,0.f}, a23 = {0.f,0.f,0.f,0.f};                \
        a01 = MFMA16(Af[t][0], Bu0.v, a01);                                    \
        a23 = MFMA16(Af[t][1], Bu1.v, a23);                                    \
        a01 = MFMA16(Af[t][2], Bu2.v, a01);                                    \
        a23 = MFMA16(Af[t][3], Bu3.v, a23);                                    \
        _Pragma("unroll")                                                      \
        for (int m = 0; m < 4; ++m) {                                          \
          float y = a01[m] + a23[m];                                           \
          y = __builtin_amdgcn_fdot2(gp01[t][m], ppu.h[0], y, false);          \
          y = __builtin_amdgcn_fdot2(gp23[t][m], ppu.h[1], y, false);          \
          float kk = fmaf(y, INV256, -LOSSC) * sv[t][m];                       \
          if (FIRST_) ks[t][m] = kk; else ks[t][m] += (W_) * kk;               \
          if (LAST_) { P0v[t][m] += DZ6_F * ks[t][m]; sv[t][m] = P0v[t][m]; }  \
          else       { sv[t][m] = fmaf((A_), kk, P0v[t][m]); }                 \
        }                                                                      \
        if (c < GB) {                                                          \
          union { f16x2 h[2]; uint2 u2; } cv;                                  \
          cv.h[0] = f16x2{(f16)sv[t][0], (f16)sv[t][1]};                       \
          cv.h[1] = f16x2{(f16)sv[t][2], (f16)sv[t][3]};                       \
          *(uint2*)&Pls[buf ^ 1][cb][16 * (2 * wid + t) + 4 * q] = cv.u2;      \
        }                                                                      \
      }                                                                        \
    } else {                                                                   \
      /* tile 6 (rows 96..99 valid on q==0) */                                 \
      f32x4 a01 = {0.f,0.f,0.f,0.f}, a23 = {0.f,0.f,0.f,0.f};                  \
      a01 = MFMA16(Af[0][0], Bu0.v, a01);                                      \
      a23 = MFMA16(Af[0][1], Bu1.v, a23);                                      \
      a01 = MFMA16(Af[0][2], Bu2.v, a01);                                      \
      a23 = MFMA16(Af[0][3], Bu3.v, a23);                                      \
      _Pragma("unroll")                                                        \
      for (int m = 0; m < 4; ++m) {                                            \
        float y = a01[m] + a23[m];                                             \
        y = __builtin_amdgcn_fdot2(gp01[0][m], ppu.h[0], y, false);            \
        y = __builtin_amdgcn_fdot2(gp23[0][m], ppu.h[1], y, false);            \
        float kk = fmaf(y, INV256, -LOSSC) * sv[0][m];                         \
        if (FIRST_) ks[0][m] = kk; else ks[0][m] += (W_) * kk;                 \
        if (LAST_) { P0v[0][m] += DZ6_F * ks[0][m]; sv[0][m] = P0v[0][m]; }    \
        else       { sv[0][m] = fmaf((A_), kk, P0v[0][m]); }                   \
      }                                                                        \
      /* pump rows 100..103: dot own k-slices, butterfly over q */             \
      float s0 = 0.f, s1 = 0.f, s2 = 0.f, s3 = 0.f;                            \
      _Pragma("unroll")                                                        \
      for (int jj = 0; jj < 4; ++jj) {                                         \
        s0 = __builtin_amdgcn_fdot2(gq[0][jj],      Bu0.h[jj], s0, false);     \
        s1 = __builtin_amdgcn_fdot2(gq[1][jj],      Bu0.h[jj], s1, false);     \
        s2 = __builtin_amdgcn_fdot2(gq[2][jj],      Bu0.h[jj], s2, false);     \
        s3 = __builtin_amdgcn_fdot2(gq[3][jj],      Bu0.h[jj], s3, false);     \
        s0 = __builtin_amdgcn_fdot2(gq[0][4 + jj],  Bu1.h[jj], s0, false);     \
        s1 = __builtin_amdgcn_fdot2(gq[1][4 + jj],  Bu1.h[jj], s1, false);     \
        s2 = __builtin_amdgcn_fdot2(gq[2][4 + jj],  Bu1.h[jj], s2, false);     \
        s3 = __builtin_amdgcn_fdot2(gq[3][4 + jj],  Bu1.h[jj], s3, false);     \
        s0 = __builtin_amdgcn_fdot2(gq[0][8 + jj],  Bu2.h[jj], s0, false);     \
        s1 = __builtin_amdgcn_fdot2(gq[1][8 + jj],  Bu2.h[jj], s1, false);     \
        s2 = __builtin_amdgcn_fdot2(gq[2][8 + jj],  Bu2.h[jj], s2, false);     \
        s3 = __builtin_amdgcn_fdot2(gq[3][8 + jj],  Bu2.h[jj], s3, false);     \
        s0 = __builtin_amdgcn_fdot2(gq[0][12 + jj], Bu3.h[jj], s0, false);     \
        s1 = __builtin_amdgcn_fdot2(gq[1][12 + jj], Bu3.h[jj], s1, false);     \
        s2 = __builtin_amdgcn_fdot2(gq[2][12 + jj], Bu3.h[jj], s2, false);     \
        s3 = __builtin_amdgcn_fdot2(gq[3][12 + jj], Bu3.h[jj], s3, false);     \
      }                                                                        \
      s0 += __shfl_xor(s0, 16); s0 += __shfl_xor(s0, 32);                      \
      s1 += __shfl_xor(s1, 16); s1 += __shfl_xor(s1, 32);                      \
      s2 += __shfl_xor(s2, 16); s2 += __shfl_xor(s2, 32);                      \
      s3 += __shfl_xor(s3, 16); s3 += __shfl_xor(s3, 32);                      \
      float su[4] = {s0, s1, s2, s3};                                          \
      _Pragma("unroll")                                                        \
      for (int r = 0; r < 4; ++r) {                                            \
        float kp = fmaf(su[r], INV256, -LOSSC) * sp[r];                        \
        if (FIRST_) kps[r] = kp; else kps[r] += (W_) * kp;                     \
        if (LAST_) { P0p[r] += DZ6_F * kps[r]; sp[r] = P0p[r]; }               \
        else       { sp[r] = fmaf((A_), kp, P0p[r]); }                         \
      }                                                                        \
      if (c < GB && q == 0) { /* rows 96..103 in ONE b128 */                   \
        union { f16x2 h[4]; uint4 u4; } cv;                                    \
        cv.h[0] = f16x2{(f16)sv[0][0], (f16)sv[0][1]};                         \
        cv.h[1] = f16x2{(f16)sv[0][2], (f16)sv[0][3]};                         \
        cv.h[2] = f16x2{(f16)sp[0], (f16)sp[1]};                               \
        cv.h[3] = f16x2{(f16)sp[2], (f16)sp[3]};                               \
        *(uint4*)&Pls[buf ^ 1][cb][96] = cv.u4;                                \
      }                                                                        \
    }                                                                          \
    __syncthreads();                                                           \
    buf ^= 1;                                                                  \
  }

__global__ __launch_bounds__(256, 2)
void raman_kernel(const float* __restrict__ x,       // (BATCH, 8)
                  const float* __restrict__ resp,    // (801,)
                  const float* __restrict__ sigwl,   // (100,)
                  float* __restrict__ out)           // (BATCH, 100)
{
    // P: rows 0..99 = signal channels, 100..103 = pumps, 104..143 = zero pad
    __shared__ __align__(16) f16 Pls[2][GB][ROWSTR];
    __shared__ float resp_s[RESPLEN + 3];
    __shared__ float sigf[NCH], siginv[NCH];
    __shared__ float pf[GB][NPUMP], pinv[GB][NPUMP], ppw[GB][NPUMP];

    const int tid  = threadIdx.x;
    const int wid  = tid >> 6;    // 0..3
    const int lane = tid & 63;
    const int c    = lane & 15;   // MFMA column; batch = c & 7 (duplicated)
    const int cb   = c & (GB - 1);
    const int q    = lane >> 4;   // quad index (k-group / C-row-group)
    const int b0   = blockIdx.x * GB;

    for (int i = tid; i < RESPLEN; i += 256) resp_s[i] = resp[i];
    for (int i = tid; i < NCH; i += 256) {
        float lam = sigwl[i];
        sigf[i]   = 299792458.0f / lam;
        siginv[i] = lam * 3.3356409519815204e-09f;   // lam/C0
    }
    if (tid < GB * NPUMP) {
        const int cc = tid >> 2, p = tid & 3;
        float lam = x[(b0 + cc) * 8 + p];
        pf[cc][p]   = 299792458.0f / lam;
        pinv[cc][p] = lam * 3.3356409519815204e-09f;
        ppw[cc][p]  = fabsf(x[(b0 + cc) * 8 + NPUMP + p]);
    }
    {   // zero both P buffers (incl. pad rows; pads are never rewritten)
        f16* pz = (f16*)Pls;
        for (int i = tid; i < 2 * GB * ROWSTR; i += 256) pz[i] = (f16)0.0f;
    }
    __syncthreads();

    // ---- A fragments: shared signal-signal gain block (fp16, x256) ----
    // v_mfma_f32_16x16x32_f16: A[row][k]: row = lane%16, k = 8*(lane/16)+j
    // C/D: col = lane&15 (batch = col&7), row = 4*(lane>>4) + m
    f16x8 Af[2][4];
    f16x2 gp01[2][4], gp23[2][4];
    #pragma unroll
    for (int t = 0; t < 2; ++t) {
        #pragma unroll
        for (int tc = 0; tc < 4; ++tc)
            Af[t][tc] = f16x8{(f16)0.f,(f16)0.f,(f16)0.f,(f16)0.f,
                              (f16)0.f,(f16)0.f,(f16)0.f,(f16)0.f};
        #pragma unroll
        for (int m = 0; m < 4; ++m) {
            gp01[t][m] = f16x2{(f16)0.f, (f16)0.f};
            gp23[t][m] = f16x2{(f16)0.f, (f16)0.f};
        }
        if (t == 0 || wid < 3) {
            const int T    = (wid < 3) ? (2 * wid + t) : 6;
            const int arow = 16 * T + c;
            const float fi = (arow < NCH) ? sigf[arow] : 0.0f;
            #pragma unroll
            for (int tc = 0; tc < 4; ++tc) {
                f16x8 a;
                #pragma unroll
                for (int j = 0; j < 8; ++j) {
                    const int k = 32 * tc + 8 * q + j;
                    float v = 0.0f;
                    if (arow < NCH && k < NCH)
                        v = gentry(fi, sigf[k], siginv[k], resp_s);
                    a[j] = (f16)v;
                }
                Af[t][tc] = a;
            }
            #pragma unroll
            for (int m = 0; m < 4; ++m) {
                const int row = 16 * T + 4 * q + m;
                float v0 = 0.f, v1 = 0.f, v2 = 0.f, v3 = 0.f;
                if (row < NCH) {
                    const float fi2 = sigf[row];
                    v0 = gentry(fi2, pf[cb][0], pinv[cb][0], resp_s);
                    v1 = gentry(fi2, pf[cb][1], pinv[cb][1], resp_s);
                    v2 = gentry(fi2, pf[cb][2], pinv[cb][2], resp_s);
                    v3 = gentry(fi2, pf[cb][3], pinv[cb][3], resp_s);
                }
                gp01[t][m] = f16x2{(f16)v0, (f16)v1};
                gp23[t][m] = f16x2{(f16)v2, (f16)v3};
            }
        }
    }

    // ---- pump-row gain slices (wid==3): gq[r][4u+jj] covers this lane's
    // resident k-slice k = 32u + 8q + 2jj (+1), matching B-fragment rows.
    f16x2 gq[4][16];
    float P0p[4] = {0.f,0.f,0.f,0.f}, sp[4] = {0.f,0.f,0.f,0.f};
    float kps[4] = {0.f,0.f,0.f,0.f};
    if (wid == 3) {
        #pragma unroll
        for (int r = 0; r < 4; ++r) {
            const float fi = pf[cb][r];
            #pragma unroll
            for (int u = 0; u < 4; ++u) {
                #pragma unroll
                for (int jj = 0; jj < 4; ++jj) {
                    const int k0 = 32 * u + 8 * q + 2 * jj;
                    const int k1 = k0 + 1;
                    float g0 = 0.f, g1 = 0.f;
                    if (k0 < NCH)
                        g0 = gentry(fi, sigf[k0], siginv[k0], resp_s);
                    else if (k0 < NCH + NPUMP)
                        g0 = gentry(fi, pf[cb][k0-NCH], pinv[cb][k0-NCH], resp_s);
                    if (k1 < NCH)
                        g1 = gentry(fi, sigf[k1], siginv[k1], resp_s);
                    else if (k1 < NCH + NPUMP)
                        g1 = gentry(fi, pf[cb][k1-NCH], pinv[cb][k1-NCH], resp_s);
                    gq[r][4 * u + jj] = f16x2{(f16)g0, (f16)g1};
                }
            }
            P0p[r] = ppw[cb][r];
            sp[r]  = P0p[r];
        }
    }

    // ---- state init (f32) + initial P into buffer 0 ----
    float P0v[2][4], sv[2][4], ks[2][4];
    #pragma unroll
    for (int t = 0; t < 2; ++t)
        #pragma unroll
        for (int m = 0; m < 4; ++m) {
            const int T = (wid < 3) ? (2 * wid + t) : 6;
            const int row = 16 * T + 4 * q + m;
            const bool live = (t == 0 || wid < 3) && row < NCH;
            P0v[t][m] = live ? 1.0e-3f : 0.0f;
            sv[t][m]  = P0v[t][m];
            ks[t][m]  = 0.0f;
        }

    int buf = 0;
    if (wid < 3) {
        if (c < GB) {
            #pragma unroll
            for (int t = 0; t < 2; ++t) {
                union { f16x2 h[2]; uint2 u2; } cv;
                cv.h[0] = f16x2{(f16)sv[t][0], (f16)sv[t][1]};
                cv.h[1] = f16x2{(f16)sv[t][2], (f16)sv[t][3]};
                *(uint2*)&Pls[0][cb][16 * (2 * wid + t) + 4 * q] = cv.u2;
            }
        }
    } else if (c < GB && q == 0) {
        union { f16x2 h[4]; uint4 u4; } cv;
        cv.h[0] = f16x2{(f16)sv[0][0], (f16)sv[0][1]};
        cv.h[1] = f16x2{(f16)sv[0][2], (f16)sv[0][3]};
        cv.h[2] = f16x2{(f16)sp[0], (f16)sp[1]};
        cv.h[3] = f16x2{(f16)sp[2], (f16)sp[3]};
        *(uint4*)&Pls[0][cb][96] = cv.u4;
    }
    __syncthreads();

    // ---- RK4 main loop: 32 steps x 4 stages, 1 barrier per stage ----
    #pragma unroll 1
    for (int step = 0; step < NSTEPS; ++step) {
        STAGE(HDZ_F, 1.0f, 1, 0)   // k1
        STAGE(HDZ_F, 2.0f, 0, 0)   // k2
        STAGE(DZ_F,  2.0f, 0, 0)   // k3
        STAGE(0.0f,  1.0f, 0, 1)   // k4 + P0 += dz/6 * ksum
    }

    // ---- output: signal rows 0..99 (float4, 16B-aligned: 400 = 25*16) ----
    if (c < GB) {
        if (wid < 3) {
            #pragma unroll
            for (int t = 0; t < 2; ++t) {
                const int row0 = 16 * (2 * wid + t) + 4 * q;
                float4 o = make_float4(P0v[t][0], P0v[t][1],
                                       P0v[t][2], P0v[t][3]);
                *(float4*)&out[(b0 + cb) * NCH + row0] = o;
            }
        } else if (q == 0) {
            float4 o = make_float4(P0v[0][0], P0v[0][1],
                                   P0v[0][2], P0v[0][3]);
            *(float4*)&out[(b0 + cb) * NCH + 96] = o;
        }
    }
}

extern "C" void kernel_launch(void* const* d_in, const int* in_sizes, int n_in,
                              void* d_out, int out_size, void* d_ws, size_t ws_size,
                              hipStream_t stream)
{
    const float* x     = (const float*)d_in[0];
    const float* resp  = (const float*)d_in[1];
    const float* sigwl = (const float*)d_in[2];
    float* out = (float*)d_out;
    raman_kernel<<<BATCH / GB, 256, 0, stream>>>(x, resp, sigwl, out);
}

// Round 7
// 136.647 us; speedup vs baseline: 1.3186x; 1.3186x over previous
//
#include <hip/hip_runtime.h>
#include <math.h>

// ================== problem constants ==================
#define BATCH   4096
#define NPUMP   4
#define NCH     100
#define RESPLEN 801

// RK4: 32 steps over 50 km (validated: absmax 1.22e-4 vs threshold 2.11e-4).
#define NSTEPS  32
#define DZ_F    1562.5f
#define HDZ_F   781.25f
#define DZ6_F   260.4166666666667f
#define LOSSC   4.605170185988092e-05f   // 0.0002 * ln(10)/10
#define INV256  0.00390625f              // undo the 2^8 G pre-scale

// ================== structure ==========================
// GB=8 batches/block, 512 blocks -> 2 INDEPENDENT blocks/CU (desynced
// barriers overlap each other's LDS/VALU/MFMA phases). 4 waves (256 thr):
//   w0: tiles {0,1}, w1: {2,3}, w2: {4,5}, w3: tile {6}.
//   pump row 100+wid computed BY WAVE wid from its resident B fragments
//   (16 dot2 + shfl_xor butterfly over q) -> gq[16] = 16 VGPR only.
// MFMA B-columns duplicate the 8 batches (same LDS address for c and c+8
// -> broadcast, bank cost halved). NO __launch_bounds__ VGPR cap (R6
// lesson: the (256,2) cap at 128 VGPR caused 107 MB of scratch spill).
#define GB      8
#define ROWSTR  144   // 288 B stride; balanced bank spans for b128 reads

typedef _Float16 f16;
typedef _Float16 f16x2 __attribute__((ext_vector_type(2)));
typedef _Float16 f16x8 __attribute__((ext_vector_type(8)));
typedef float    f32x4 __attribute__((ext_vector_type(4)));

union u8x { f16x8 v; f16x2 h[4]; };

#define MFMA16(Aa, Bb, Cc) __builtin_amdgcn_mfma_f32_16x16x32_f16((Aa), (Bb), (Cc), 0, 0, 0)

// Gain entry, scaled by 256 (3.2e12 = 1.25e10 * 2^8) so fp16-quantized
// near-diagonal entries stay normal. Consumers multiply y by INV256.
__device__ __forceinline__ float gentry(float fi, float fj, float invfj,
                                        const float* __restrict__ resp_s)
{
    float D    = fj - fi;
    float ad   = fabsf(D);
    float fidx = ad * 2.0e-11f;          // 1/DF
    int   i0   = (int)fidx;
    i0 = i0 > (RESPLEN - 2) ? (RESPLEN - 2) : i0;
    float w  = fidx - (float)i0;
    float g  = resp_s[i0] * (1.0f - w) + resp_s[i0 + 1] * w;
    g = (D < 0.0f) ? -g : g;
    float ratio = fi * invfj;
    float m  = fmaxf(1.0f, ratio);
    return g * m * 3.2e12f;              // (1/EFFECTIVE_AREA) * 256
}

// One RK stage. Reads P (fp16) from Pls[buf], writes next-stage P to
// Pls[buf^1], one barrier. FIRST_/LAST_ are 0/1 literals.
#define STAGE(A_, W_, FIRST_, LAST_)                                           \
  {                                                                            \
    const f16* pb = (const f16*)&Pls[buf][cb][0];                              \
    u8x Bu0, Bu1, Bu2, Bu3;                                                    \
    Bu0.v = *(const f16x8*)(pb + 8 * q);                                       \
    Bu1.v = *(const f16x8*)(pb + 32 + 8 * q);                                  \
    Bu2.v = *(const f16x8*)(pb + 64 + 8 * q);                                  \
    Bu3.v = *(const f16x8*)(pb + 96 + 8 * q);                                  \
    union { uint2 u2; f16x2 h[2]; } ppu;                                       \
    ppu.u2 = *(const uint2*)(pb + 100);                                        \
    /* issue MFMAs first so matrix pipe runs under the pump VALU */            \
    f32x4 a01 = {0.f,0.f,0.f,0.f}, a23 = {0.f,0.f,0.f,0.f};                    \
    a01 = MFMA16(AfA[0], Bu0.v, a01);                                          \
    a23 = MFMA16(AfA[1], Bu1.v, a23);                                          \
    a01 = MFMA16(AfA[2], Bu2.v, a01);                                          \
    a23 = MFMA16(AfA[3], Bu3.v, a23);                                          \
    f32x4 b01 = {0.f,0.f,0.f,0.f}, b23 = {0.f,0.f,0.f,0.f};                    \
    if (wid < 3) {                                                             \
      b01 = MFMA16(AfB[0], Bu0.v, b01);                                        \
      b23 = MFMA16(AfB[1], Bu1.v, b23);                                        \
      b01 = MFMA16(AfB[2], Bu2.v, b01);                                        \
      b23 = MFMA16(AfB[3], Bu3.v, b23);                                        \
    }                                                                          \
    /* pump row 100+wid: dot own resident k-slices, butterfly over q */        \
    float s0 = 0.0f;                                                           \
    _Pragma("unroll")                                                          \
    for (int jj = 0; jj < 4; ++jj) {                                           \
      s0 = __builtin_amdgcn_fdot2(gq[jj],      Bu0.h[jj], s0, false);          \
      s0 = __builtin_amdgcn_fdot2(gq[4 + jj],  Bu1.h[jj], s0, false);          \
      s0 = __builtin_amdgcn_fdot2(gq[8 + jj],  Bu2.h[jj], s0, false);          \
      s0 = __builtin_amdgcn_fdot2(gq[12 + jj], Bu3.h[jj], s0, false);          \
    }                                                                          \
    s0 += __shfl_xor(s0, 16);                                                  \
    s0 += __shfl_xor(s0, 32);                                                  \
    {                                                                          \
      float kp = fmaf(s0, INV256, -LOSSC) * sp;                                \
      if (FIRST_) kps = kp; else kps += (W_) * kp;                             \
      if (LAST_) { P0p += DZ6_F * kps; sp = P0p; }                             \
      else       { sp = fmaf((A_), kp, P0p); }                                 \
    }                                                                          \
    { /* tile A epilogue */                                                    \
      _Pragma("unroll")                                                        \
      for (int m = 0; m < 4; ++m) {                                            \
        float y = a01[m] + a23[m];                                             \
        y = __builtin_amdgcn_fdot2(gpA01[m], ppu.h[0], y, false);              \
        y = __builtin_amdgcn_fdot2(gpA23[m], ppu.h[1], y, false);              \
        float kk = fmaf(y, INV256, -LOSSC) * svA[m];                           \
        if (FIRST_) ksA[m] = kk; else ksA[m] += (W_) * kk;                     \
        if (LAST_) { P0vA[m] += DZ6_F * ksA[m]; svA[m] = P0vA[m]; }            \
        else       { svA[m] = fmaf((A_), kk, P0vA[m]); }                       \
      }                                                                        \
      if (c < GB && (wid < 3 || q == 0)) {                                     \
        union { f16x2 h[2]; uint2 u2; } cv;                                    \
        cv.h[0] = f16x2{(f16)svA[0], (f16)svA[1]};                             \
        cv.h[1] = f16x2{(f16)svA[2], (f16)svA[3]};                             \
        *(uint2*)&Pls[buf ^ 1][cb][rowA0] = cv.u2;                             \
      }                                                                        \
    }                                                                          \
    if (wid < 3) { /* tile B epilogue (rows all < 100) */                      \
      _Pragma("unroll")                                                        \
      for (int m = 0; m < 4; ++m) {                                            \
        float y = b01[m] + b23[m];                                             \
        y = __builtin_amdgcn_fdot2(gpB01[m], ppu.h[0], y, false);              \
        y = __builtin_amdgcn_fdot2(gpB23[m], ppu.h[1], y, false);              \
        float kk = fmaf(y, INV256, -LOSSC) * svB[m];                           \
        if (FIRST_) ksB[m] = kk; else ksB[m] += (W_) * kk;                     \
        if (LAST_) { P0vB[m] += DZ6_F * ksB[m]; svB[m] = P0vB[m]; }            \
        else       { svB[m] = fmaf((A_), kk, P0vB[m]); }                       \
      }                                                                        \
      if (c < GB) {                                                            \
        union { f16x2 h[2]; uint2 u2; } cv;                                    \
        cv.h[0] = f16x2{(f16)svB[0], (f16)svB[1]};                             \
        cv.h[1] = f16x2{(f16)svB[2], (f16)svB[3]};                             \
        *(uint2*)&Pls[buf ^ 1][cb][rowB0] = cv.u2;                             \
      }                                                                        \
    }                                                                          \
    if (c < GB && q == 0) Pls[buf ^ 1][cb][NCH + wid] = (f16)sp;               \
    __syncthreads();                                                           \
    buf ^= 1;                                                                  \
  }

__global__ __launch_bounds__(256)
void raman_kernel(const float* __restrict__ x,       // (BATCH, 8)
                  const float* __restrict__ resp,    // (801,)
                  const float* __restrict__ sigwl,   // (100,)
                  float* __restrict__ out)           // (BATCH, 100)
{
    // P: rows 0..99 = signal channels, 100..103 = pumps, 104..143 = zero pad
    __shared__ __align__(16) f16 Pls[2][GB][ROWSTR];
    __shared__ float resp_s[RESPLEN + 3];
    __shared__ float sigf[NCH], siginv[NCH];
    __shared__ float pf[GB][NPUMP], pinv[GB][NPUMP], ppw[GB][NPUMP];

    const int tid  = threadIdx.x;
    const int wid  = tid >> 6;    // 0..3
    const int lane = tid & 63;
    const int c    = lane & 15;   // MFMA column; batch = c & 7 (duplicated)
    const int cb   = c & (GB - 1);
    const int q    = lane >> 4;   // quad index (k-group / C-row-group)
    const int b0   = blockIdx.x * GB;
    const int TA   = (wid < 3) ? (2 * wid) : 6;
    const int rowA0 = 16 * TA + 4 * q;
    const int rowB0 = 16 * (2 * wid + 1) + 4 * q;   // wid<3 only

    for (int i = tid; i < RESPLEN; i += 256) resp_s[i] = resp[i];
    for (int i = tid; i < NCH; i += 256) {
        float lam = sigwl[i];
        sigf[i]   = 299792458.0f / lam;
        siginv[i] = lam * 3.3356409519815204e-09f;   // lam/C0
    }
    if (tid < GB * NPUMP) {
        const int cc = tid >> 2, p = tid & 3;
        float lam = x[(b0 + cc) * 8 + p];
        pf[cc][p]   = 299792458.0f / lam;
        pinv[cc][p] = lam * 3.3356409519815204e-09f;
        ppw[cc][p]  = fabsf(x[(b0 + cc) * 8 + NPUMP + p]);
    }
    {   // zero both P buffers (incl. pad rows; pads are never rewritten)
        f16* pz = (f16*)Pls;
        for (int i = tid; i < 2 * GB * ROWSTR; i += 256) pz[i] = (f16)0.0f;
    }
    __syncthreads();

    // ---- A fragments: shared signal-signal gain block (fp16, x256) ----
    // v_mfma_f32_16x16x32_f16: A[row][k]: row = lane%16, k = 8*(lane/16)+j
    // C/D: col = lane&15 (batch = col&7), row = 4*(lane>>4) + m
    f16x8 AfA[4], AfB[4];
    f16x2 gpA01[4], gpA23[4], gpB01[4], gpB23[4];
    {
        const int arow = 16 * TA + c;
        const float fi = (arow < NCH) ? sigf[arow] : 0.0f;
        #pragma unroll
        for (int t = 0; t < 4; ++t) {
            f16x8 a;
            #pragma unroll
            for (int j = 0; j < 8; ++j) {
                const int k = 32 * t + 8 * q + j;
                float v = 0.0f;
                if (arow < NCH && k < NCH)
                    v = gentry(fi, sigf[k], siginv[k], resp_s);
                a[j] = (f16)v;
            }
            AfA[t] = a;
        }
        #pragma unroll
        for (int m = 0; m < 4; ++m) {
            const int row = 16 * TA + 4 * q + m;
            float v0 = 0.f, v1 = 0.f, v2 = 0.f, v3 = 0.f;
            if (row < NCH) {
                const float fi2 = sigf[row];
                v0 = gentry(fi2, pf[cb][0], pinv[cb][0], resp_s);
                v1 = gentry(fi2, pf[cb][1], pinv[cb][1], resp_s);
                v2 = gentry(fi2, pf[cb][2], pinv[cb][2], resp_s);
                v3 = gentry(fi2, pf[cb][3], pinv[cb][3], resp_s);
            }
            gpA01[m] = f16x2{(f16)v0, (f16)v1};
            gpA23[m] = f16x2{(f16)v2, (f16)v3};
        }
    }
    #pragma unroll
    for (int t = 0; t < 4; ++t)
        AfB[t] = f16x8{(f16)0.f,(f16)0.f,(f16)0.f,(f16)0.f,
                       (f16)0.f,(f16)0.f,(f16)0.f,(f16)0.f};
    #pragma unroll
    for (int m = 0; m < 4; ++m) {
        gpB01[m] = f16x2{(f16)0.f, (f16)0.f};
        gpB23[m] = f16x2{(f16)0.f, (f16)0.f};
    }
    if (wid < 3) {
        const int TB   = 2 * wid + 1;
        const int arow = 16 * TB + c;
        const float fi = sigf[arow];            // TB rows all < 100
        #pragma unroll
        for (int t = 0; t < 4; ++t) {
            f16x8 a;
            #pragma unroll
            for (int j = 0; j < 8; ++j) {
                const int k = 32 * t + 8 * q + j;
                float v = 0.0f;
                if (k < NCH)
                    v = gentry(fi, sigf[k], siginv[k], resp_s);
                a[j] = (f16)v;
            }
            AfB[t] = a;
        }
        #pragma unroll
        for (int m = 0; m < 4; ++m) {
            const int row = 16 * TB + 4 * q + m;
            const float fi2 = sigf[row];
            gpB01[m] = f16x2{(f16)gentry(fi2, pf[cb][0], pinv[cb][0], resp_s),
                             (f16)gentry(fi2, pf[cb][1], pinv[cb][1], resp_s)};
            gpB23[m] = f16x2{(f16)gentry(fi2, pf[cb][2], pinv[cb][2], resp_s),
                             (f16)gentry(fi2, pf[cb][3], pinv[cb][3], resp_s)};
        }
    }

    // ---- pump-row gain slice: wave wid owns pump row 100+wid.
    // gq[4u+jj] covers this lane's resident k = 32u + 8q + 2jj (+1).
    f16x2 gq[16];
    float P0p, sp, kps = 0.0f;
    {
        const float fi = pf[cb][wid];
        #pragma unroll
        for (int u = 0; u < 4; ++u) {
            #pragma unroll
            for (int jj = 0; jj < 4; ++jj) {
                const int k0 = 32 * u + 8 * q + 2 * jj;
                const int k1 = k0 + 1;
                float g0 = 0.f, g1 = 0.f;
                if (k0 < NCH)
                    g0 = gentry(fi, sigf[k0], siginv[k0], resp_s);
                else if (k0 < NCH + NPUMP)
                    g0 = gentry(fi, pf[cb][k0-NCH], pinv[cb][k0-NCH], resp_s);
                if (k1 < NCH)
                    g1 = gentry(fi, sigf[k1], siginv[k1], resp_s);
                else if (k1 < NCH + NPUMP)
                    g1 = gentry(fi, pf[cb][k1-NCH], pinv[cb][k1-NCH], resp_s);
                gq[4 * u + jj] = f16x2{(f16)g0, (f16)g1};
            }
        }
        P0p = ppw[cb][wid];
        sp  = P0p;
    }

    // ---- state init (f32) + initial P into buffer 0 ----
    float P0vA[4], svA[4], ksA[4], P0vB[4], svB[4], ksB[4];
    #pragma unroll
    for (int m = 0; m < 4; ++m) {
        P0vA[m] = (rowA0 + m < NCH) ? 1.0e-3f : 0.0f;
        svA[m]  = P0vA[m];
        ksA[m]  = 0.0f;
        P0vB[m] = (wid < 3) ? 1.0e-3f : 0.0f;
        svB[m]  = P0vB[m];
        ksB[m]  = 0.0f;
    }

    int buf = 0;
    if (c < GB && (wid < 3 || q == 0)) {
        union { f16x2 h[2]; uint2 u2; } cv;
        cv.h[0] = f16x2{(f16)svA[0], (f16)svA[1]};
        cv.h[1] = f16x2{(f16)svA[2], (f16)svA[3]};
        *(uint2*)&Pls[0][cb][rowA0] = cv.u2;
    }
    if (wid < 3 && c < GB) {
        union { f16x2 h[2]; uint2 u2; } cv;
        cv.h[0] = f16x2{(f16)svB[0], (f16)svB[1]};
        cv.h[1] = f16x2{(f16)svB[2], (f16)svB[3]};
        *(uint2*)&Pls[0][cb][rowB0] = cv.u2;
    }
    if (c < GB && q == 0) Pls[0][cb][NCH + wid] = (f16)sp;
    __syncthreads();

    // ---- RK4 main loop: 32 steps x 4 stages, 1 barrier per stage ----
    #pragma unroll 1
    for (int step = 0; step < NSTEPS; ++step) {
        STAGE(HDZ_F, 1.0f, 1, 0)   // k1
        STAGE(HDZ_F, 2.0f, 0, 0)   // k2
        STAGE(DZ_F,  2.0f, 0, 0)   // k3
        STAGE(0.0f,  1.0f, 0, 1)   // k4 + P0 += dz/6 * ksum
    }

    // ---- output: signal rows 0..99 (float4, 16B-aligned: 400 = 25*16) ----
    if (c < GB) {
        if (wid < 3 || q == 0) {
            float4 o = make_float4(P0vA[0], P0vA[1], P0vA[2], P0vA[3]);
            *(float4*)&out[(b0 + cb) * NCH + rowA0] = o;
        }
        if (wid < 3) {
            float4 o = make_float4(P0vB[0], P0vB[1], P0vB[2], P0vB[3]);
            *(float4*)&out[(b0 + cb) * NCH + rowB0] = o;
        }
    }
}

extern "C" void kernel_launch(void* const* d_in, const int* in_sizes, int n_in,
                              void* d_out, int out_size, void* d_ws, size_t ws_size,
                              hipStream_t stream)
{
    const float* x     = (const float*)d_in[0];
    const float* resp  = (const float*)d_in[1];
    const float* sigwl = (const float*)d_in[2];
    float* out = (float*)d_out;
    raman_kernel<<<BATCH / GB, 256, 0, stream>>>(x, resp, sigwl, out);
}

// Round 8
// 109.124 us; speedup vs baseline: 1.6512x; 1.2522x over previous
//
#include <hip/hip_runtime.h>
#include <math.h>

// ================== problem constants ==================
#define BATCH   4096
#define NPUMP   4
#define NCH     100
#define RESPLEN 801

// RK4: 32 steps over 50 km (validated: absmax 1.22e-4 vs threshold 2.11e-4).
#define NSTEPS  32
#define DZ_F    1562.5f
#define HDZ_F   781.25f
#define DZ6_F   260.4166666666667f
#define LOSSC   4.605170185988092e-05f   // 0.0002 * ln(10)/10
#define INV256  0.00390625f              // undo the 2^8 G pre-scale

// ================== structure ==========================
// R8: 7 waves (448 thr), GB=16 batches = all 16 MFMA columns (NO
// duplication - the R5/R7 mistake), grid 256 = 1 block/CU, ~2 waves/SIMD.
// Wave w owns tile w (rows 16w..16w+15): 5 LDS reads, 4 MFMA, epilogue.
// Pump row 100+w lives in wave w (w<4), computed from the wave's RESIDENT
// B-fragments: 16 dot2 + shfl_xor(16/32) butterfly (R7-validated path).
// This deletes R3's wave 7 (13 broadcast reads + 52-deep serial dot2 tail):
// reads/stage/CU 48 -> 35.
// ROWSTR=136 f16 (272 B): 68 dw == 4 (mod 32) -> quarter-wave b128 reads
// land 2 dw/bank (minimal); b64 writes 2-way (free).
#define GB      16
#define ROWSTR  136

typedef _Float16 f16;
typedef _Float16 f16x2 __attribute__((ext_vector_type(2)));
typedef _Float16 f16x8 __attribute__((ext_vector_type(8)));
typedef float    f32x4 __attribute__((ext_vector_type(4)));

union u8x { f16x8 v; f16x2 h[4]; };

#define MFMA16(Aa, Bb, Cc) __builtin_amdgcn_mfma_f32_16x16x32_f16((Aa), (Bb), (Cc), 0, 0, 0)

// Gain entry, scaled by 256 (3.2e12 = 1.25e10 * 2^8) so fp16-quantized
// near-diagonal entries stay normal. Consumers multiply y by INV256.
__device__ __forceinline__ float gentry(float fi, float fj, float invfj,
                                        const float* __restrict__ resp_s)
{
    float D    = fj - fi;
    float ad   = fabsf(D);
    float fidx = ad * 2.0e-11f;          // 1/DF
    int   i0   = (int)fidx;
    i0 = i0 > (RESPLEN - 2) ? (RESPLEN - 2) : i0;
    float w  = fidx - (float)i0;
    float g  = resp_s[i0] * (1.0f - w) + resp_s[i0 + 1] * w;
    g = (D < 0.0f) ? -g : g;
    float ratio = fi * invfj;
    float m  = fmaxf(1.0f, ratio);
    return g * m * 3.2e12f;              // (1/EFFECTIVE_AREA) * 256
}

// One RK stage. Reads P (fp16) from Pls[buf], writes next-stage P to
// Pls[buf^1], one barrier. FIRST_/LAST_ are 0/1 literals.
#define STAGE(A_, W_, FIRST_, LAST_)                                           \
  {                                                                            \
    const f16* pb = (const f16*)&Pls[buf][c][0];                               \
    u8x Bu0, Bu1, Bu2, Bu3;                                                    \
    Bu0.v = *(const f16x8*)(pb + 8 * q);                                       \
    Bu1.v = *(const f16x8*)(pb + 32 + 8 * q);                                  \
    Bu2.v = *(const f16x8*)(pb + 64 + 8 * q);                                  \
    Bu3.v = *(const f16x8*)(pb + 96 + 8 * q);                                  \
    union { uint2 u2; f16x2 h[2]; } ppu;                                       \
    ppu.u2 = *(const uint2*)(pb + 100);                                        \
    /* MFMAs first: matrix pipe runs under the pump VALU below */              \
    f32x4 a01 = {0.f,0.f,0.f,0.f}, a23 = {0.f,0.f,0.f,0.f};                    \
    a01 = MFMA16(Af[0], Bu0.v, a01);                                           \
    a23 = MFMA16(Af[1], Bu1.v, a23);                                           \
    a01 = MFMA16(Af[2], Bu2.v, a01);                                           \
    a23 = MFMA16(Af[3], Bu3.v, a23);                                           \
    if (wid < 4) { /* pump row 100+wid from resident B regs */                 \
      float s0 = 0.0f;                                                         \
      _Pragma("unroll")                                                        \
      for (int jj = 0; jj < 4; ++jj) {                                         \
        s0 = __builtin_amdgcn_fdot2(gq[jj],      Bu0.h[jj], s0, false);        \
        s0 = __builtin_amdgcn_fdot2(gq[4 + jj],  Bu1.h[jj], s0, false);        \
        s0 = __builtin_amdgcn_fdot2(gq[8 + jj],  Bu2.h[jj], s0, false);        \
        s0 = __builtin_amdgcn_fdot2(gq[12 + jj], Bu3.h[jj], s0, false);        \
      }                                                                        \
      s0 += __shfl_xor(s0, 16);                                                \
      s0 += __shfl_xor(s0, 32);                                                \
      float kp = fmaf(s0, INV256, -LOSSC) * sp;                                \
      if (FIRST_) kps = kp; else kps += (W_) * kp;                             \
      if (LAST_) { P0p += DZ6_F * kps; sp = P0p; }                             \
      else       { sp = fmaf((A_), kp, P0p); }                                 \
      if (q == 0) Pls[buf ^ 1][c][NCH + wid] = (f16)sp;                        \
    }                                                                          \
    { /* tile epilogue (rows row0..row0+3) */                                  \
      _Pragma("unroll")                                                        \
      for (int m = 0; m < 4; ++m) {                                            \
        float y = a01[m] + a23[m];                                             \
        y = __builtin_amdgcn_fdot2(gp01[m], ppu.h[0], y, false);               \
        y = __builtin_amdgcn_fdot2(gp23[m], ppu.h[1], y, false);               \
        float kk = fmaf(y, INV256, -LOSSC) * sv[m];                            \
        if (FIRST_) ks[m] = kk; else ks[m] += (W_) * kk;                       \
        if (LAST_) { P0v[m] += DZ6_F * ks[m]; sv[m] = P0v[m]; }                \
        else       { sv[m] = fmaf((A_), kk, P0v[m]); }                         \
      }                                                                        \
      if (row0 < NCH) {                                                        \
        union { f16x2 h[2]; uint2 u2; } cv;                                    \
        cv.h[0] = f16x2{(f16)sv[0], (f16)sv[1]};                               \
        cv.h[1] = f16x2{(f16)sv[2], (f16)sv[3]};                               \
        *(uint2*)&Pls[buf ^ 1][c][row0] = cv.u2;                               \
      }                                                                        \
    }                                                                          \
    __syncthreads();                                                           \
    buf ^= 1;                                                                  \
  }

__global__ __launch_bounds__(448)
void raman_kernel(const float* __restrict__ x,       // (BATCH, 8)
                  const float* __restrict__ resp,    // (801,)
                  const float* __restrict__ sigwl,   // (100,)
                  float* __restrict__ out)           // (BATCH, 100)
{
    // P: rows 0..99 = signal channels, 100..103 = pumps, 104..135 = zero pad
    __shared__ __align__(16) f16 Pls[2][GB][ROWSTR];
    __shared__ float resp_s[RESPLEN + 3];
    __shared__ float sigf[NCH], siginv[NCH];
    __shared__ float pf[GB][NPUMP], pinv[GB][NPUMP], ppw[GB][NPUMP];

    const int tid  = threadIdx.x;
    const int wid  = tid >> 6;    // 0..6 (wave = tile)
    const int lane = tid & 63;
    const int c    = lane & 15;   // MFMA column = batch within group
    const int q    = lane >> 4;   // quad index (k-group / C-row-group)
    const int b0   = blockIdx.x * GB;
    const int row0 = 16 * wid + 4 * q;   // C rows row0..row0+3

    for (int i = tid; i < RESPLEN; i += 448) resp_s[i] = resp[i];
    for (int i = tid; i < NCH; i += 448) {
        float lam = sigwl[i];
        sigf[i]   = 299792458.0f / lam;
        siginv[i] = lam * 3.3356409519815204e-09f;   // lam/C0
    }
    if (tid < GB * NPUMP) {
        const int cc = tid >> 2, p = tid & 3;
        float lam = x[(b0 + cc) * 8 + p];
        pf[cc][p]   = 299792458.0f / lam;
        pinv[cc][p] = lam * 3.3356409519815204e-09f;
        ppw[cc][p]  = fabsf(x[(b0 + cc) * 8 + NPUMP + p]);
    }
    {   // zero both P buffers (incl. pad rows; pads are never rewritten)
        f16* pz = (f16*)Pls;
        for (int i = tid; i < 2 * GB * ROWSTR; i += 448) pz[i] = (f16)0.0f;
    }
    __syncthreads();

    // ---- A fragments: shared signal-signal gain block (fp16, x256) ----
    // v_mfma_f32_16x16x32_f16: A[row][k]: row = lane%16, k = 8*(lane/16)+j
    // C/D: col = lane&15 (=batch c), row = 4*(lane>>4) + m
    f16x8 Af[4];
    f16x2 gp01[4], gp23[4];
    {
        const int arow = 16 * wid + c;
        const float fi = (arow < NCH) ? sigf[arow] : 0.0f;
        #pragma unroll
        for (int t = 0; t < 4; ++t) {
            f16x8 a;
            #pragma unroll
            for (int j = 0; j < 8; ++j) {
                const int k = 32 * t + 8 * q + j;
                float v = 0.0f;
                // pump columns (k>=100) excluded: added via gp01/gp23 dot2s
                if (arow < NCH && k < NCH)
                    v = gentry(fi, sigf[k], siginv[k], resp_s);
                a[j] = (f16)v;
            }
            Af[t] = a;
        }
        #pragma unroll
        for (int m = 0; m < 4; ++m) {
            const int row = row0 + m;
            float v0 = 0.f, v1 = 0.f, v2 = 0.f, v3 = 0.f;
            if (row < NCH) {
                const float fi2 = sigf[row];
                v0 = gentry(fi2, pf[c][0], pinv[c][0], resp_s);
                v1 = gentry(fi2, pf[c][1], pinv[c][1], resp_s);
                v2 = gentry(fi2, pf[c][2], pinv[c][2], resp_s);
                v3 = gentry(fi2, pf[c][3], pinv[c][3], resp_s);
            }
            gp01[m] = f16x2{(f16)v0, (f16)v1};
            gp23[m] = f16x2{(f16)v2, (f16)v3};
        }
    }

    // ---- pump-row gain slice (wid<4): wave wid owns pump row 100+wid.
    // gq[4u+jj] covers this lane's resident k = 32u + 8q + 2jj (+1).
    f16x2 gq[16];
    float P0p = 0.0f, sp = 0.0f, kps = 0.0f;
    if (wid < 4) {
        const float fi = pf[c][wid];
        #pragma unroll
        for (int u = 0; u < 4; ++u) {
            #pragma unroll
            for (int jj = 0; jj < 4; ++jj) {
                const int k0 = 32 * u + 8 * q + 2 * jj;
                const int k1 = k0 + 1;
                float g0 = 0.f, g1 = 0.f;
                if (k0 < NCH)
                    g0 = gentry(fi, sigf[k0], siginv[k0], resp_s);
                else if (k0 < NCH + NPUMP)
                    g0 = gentry(fi, pf[c][k0-NCH], pinv[c][k0-NCH], resp_s);
                if (k1 < NCH)
                    g1 = gentry(fi, sigf[k1], siginv[k1], resp_s);
                else if (k1 < NCH + NPUMP)
                    g1 = gentry(fi, pf[c][k1-NCH], pinv[c][k1-NCH], resp_s);
                gq[4 * u + jj] = f16x2{(f16)g0, (f16)g1};
            }
        }
        P0p = ppw[c][wid];
        sp  = P0p;
    }

    // ---- state init (f32, C-layout) + initial P into buffer 0 ----
    float P0v[4], sv[4], ks[4];
    #pragma unroll
    for (int m = 0; m < 4; ++m) {
        P0v[m] = (row0 + m < NCH) ? 1.0e-3f : 0.0f;
        sv[m]  = P0v[m];
        ks[m]  = 0.0f;
    }

    int buf = 0;
    if (row0 < NCH) {
        union { f16x2 h[2]; uint2 u2; } cv;
        cv.h[0] = f16x2{(f16)sv[0], (f16)sv[1]};
        cv.h[1] = f16x2{(f16)sv[2], (f16)sv[3]};
        *(uint2*)&Pls[0][c][row0] = cv.u2;
    }
    if (wid < 4 && q == 0) Pls[0][c][NCH + wid] = (f16)sp;
    __syncthreads();

    // ---- RK4 main loop: 32 steps x 4 stages, 1 barrier per stage ----
    #pragma unroll 1
    for (int step = 0; step < NSTEPS; ++step) {
        STAGE(HDZ_F, 1.0f, 1, 0)   // k1
        STAGE(HDZ_F, 2.0f, 0, 0)   // k2
        STAGE(DZ_F,  2.0f, 0, 0)   // k3
        STAGE(0.0f,  1.0f, 0, 1)   // k4 + P0 += dz/6 * ksum
    }

    // ---- output: signal rows 0..99 (float4, 16B-aligned: 400 = 25*16) ----
    if (row0 < NCH) {
        float4 o = make_float4(P0v[0], P0v[1], P0v[2], P0v[3]);
        *(float4*)&out[(b0 + c) * NCH + row0] = o;
    }
}

extern "C" void kernel_launch(void* const* d_in, const int* in_sizes, int n_in,
                              void* d_out, int out_size, void* d_ws, size_t ws_size,
                              hipStream_t stream)
{
    const float* x     = (const float*)d_in[0];
    const float* resp  = (const float*)d_in[1];
    const float* sigwl = (const float*)d_in[2];
    float* out = (float*)d_out;
    raman_kernel<<<BATCH / GB, 448, 0, stream>>>(x, resp, sigwl, out);
}